// Round 1
// baseline (17337.421 us; speedup 1.0000x reference)
//
#include <hip/hip_runtime.h>

typedef _Float16 f16x8 __attribute__((ext_vector_type(8)));
typedef float    f32x4 __attribute__((ext_vector_type(4)));

#define DEVINL __device__ __forceinline__

namespace {
constexpr int Tt = 256, Ff = 128, Hh = 256, Uu = 512, OUTo = 128;
constexpr int Zz = Ff + Hh;            // 384
constexpr int BT = 16;                 // batch rows per block
constexpr int NBLK = 32;               // 512 / 16

// ws layout (f16 element offsets)
constexpr int W1F_OFF = 0;             // [32 nt][12 kt][64 lane][8]
constexpr int W2F_OFF = 196608;        // [32 nt][16 kt][64][8]
constexpr int WHF_OFF = 458752;        // [4 head][16 nt][16 kt][64][8]
constexpr int WOF_OFF = 983040;        // [8 nt][8 kt][64][8]
constexpr int WTOT    = 1015808;
}

// ---------------- weight prep: f32 row-major -> fp16 MFMA-fragment layout ----------------
__global__ void prep_weights(const float* __restrict__ W1, const float* __restrict__ W2,
                             const float* __restrict__ Wff1, const float* __restrict__ Wff2,
                             const float* __restrict__ Wta, const float* __restrict__ Wtb,
                             const float* __restrict__ Wout, _Float16* __restrict__ ws)
{
    int o = blockIdx.x * blockDim.x + threadIdx.x;
    if (o >= WTOT) return;
    const float* W; int N, KT; _Float16* dst; int lo;
    if (o < W2F_OFF)      { W = W1; N = 512; KT = 12; dst = ws + W1F_OFF; lo = o; }
    else if (o < WHF_OFF) { W = W2; N = 512; KT = 16; dst = ws + W2F_OFF; lo = o - W2F_OFF; }
    else if (o < WOF_OFF) {
        int ll = o - WHF_OFF; int h = ll >> 17; lo = ll & 131071;
        W = (h == 0) ? Wff1 : (h == 1) ? Wff2 : (h == 2) ? Wta : Wtb;
        N = 256; KT = 16; dst = ws + WHF_OFF + (h << 17);
    }
    else                  { W = Wout; N = 128; KT = 8; dst = ws + WOF_OFF; lo = o - WOF_OFF; }
    int j = lo & 7, l = (lo >> 3) & 63, g = lo >> 9;
    int kt = g % KT, nt = g / KT;
    int k = kt * 32 + ((l >> 4) << 3) + j;   // A/B frag: k = ktile*32 + (lane>>4)*8 + j
    int n = nt * 16 + (l & 15);              // col  = ntile*16 + (lane&15)
    dst[lo] = (_Float16)W[k * N + n];
}

// ---------------- activation helpers (graceful at +-inf) ----------------
DEVINL float fast_tanh(float v) {
    float e = __expf(2.0f * v);
    return 1.0f - 2.0f / (e + 1.0f);
}
DEVINL float fast_sigmoid(float v) { return 1.0f / (1.0f + __expf(-v)); }
DEVINL float lecun_act(float v)    { return 1.7159f * fast_tanh(0.666f * v); }

DEVINL f32x4 zero4() { f32x4 z = {0.f, 0.f, 0.f, 0.f}; return z; }

// ---------------- inner GEMM: LDS A-fragments x global fragment-layout B ----------------
// A0: &Abuf[lane&15][(lane>>4)*8]; per kt advance 32 f16 along the row.
// Bp[r]: per-tile fragment base (+lane*8); per kt advance 512 f16 (one [64][8] block).
template<int NREP, int KT>
DEVINL void run_gemm(f32x4* acc, const _Float16* A0, const _Float16* const* Bp) {
    f16x8 b0[NREP], b1[NREP];
#pragma unroll
    for (int r = 0; r < NREP; ++r) b0[r] = *(const f16x8*)(Bp[r]);
#pragma unroll
    for (int kt = 0; kt < KT; kt += 2) {
#pragma unroll
        for (int r = 0; r < NREP; ++r) b1[r] = *(const f16x8*)(Bp[r] + (kt + 1) * 512);
        f16x8 a0 = *(const f16x8*)(A0 + kt * 32);
#pragma unroll
        for (int r = 0; r < NREP; ++r)
            acc[r] = __builtin_amdgcn_mfma_f32_16x16x32_f16(a0, b0[r], acc[r], 0, 0, 0);
        if (kt + 2 < KT) {
#pragma unroll
            for (int r = 0; r < NREP; ++r) b0[r] = *(const f16x8*)(Bp[r] + (kt + 2) * 512);
        }
        f16x8 a1 = *(const f16x8*)(A0 + (kt + 1) * 32);
#pragma unroll
        for (int r = 0; r < NREP; ++r)
            acc[r] = __builtin_amdgcn_mfma_f32_16x16x32_f16(a1, b1[r], acc[r], 0, 0, 0);
    }
}

// ---------------- main: 32 blocks x 16 rows, full T loop per block ----------------
__global__ __launch_bounds__(512, 2)
void cfc_main(const float* __restrict__ x, const float* __restrict__ ts,
              const float* __restrict__ b1g, const float* __restrict__ b2g,
              const float* __restrict__ bff1g, const float* __restrict__ bff2g,
              const float* __restrict__ btag, const float* __restrict__ btbg,
              const float* __restrict__ boutg,
              const _Float16* __restrict__ wsbase,
              float* __restrict__ out)
{
    __shared__ _Float16 zbuf[BT][Zz + 8];    // [x(0:128) | h(128:384)] fp16, stride 392
    __shared__ _Float16 z1buf[BT][Uu + 8];   // stride 520
    __shared__ _Float16 z2buf[BT][Uu + 8];
    __shared__ float    biasbuf[2176];       // b1|b2|bff1|bff2|bta|btb|bout

    const _Float16* w1f = wsbase + W1F_OFF;
    const _Float16* w2f = wsbase + W2F_OFF;
    const _Float16* whf = wsbase + WHF_OFF;
    const _Float16* wof = wsbase + WOF_OFF;

    const int tid = threadIdx.x;
    const int l = tid & 63, w = tid >> 6;
    const int r0 = blockIdx.x * BT;
    const int lc = l & 15;   // col within tile (B/C) == row within tile (A)
    const int lg = l >> 4;   // k-group / C row-group

    // ---- prologue: biases -> LDS, h := 0, x(0) -> zbuf ----
    for (int i = tid; i < 2176; i += 512) {
        float v;
        if      (i < 512)  v = b1g[i];
        else if (i < 1024) v = b2g[i - 512];
        else if (i < 1280) v = bff1g[i - 1024];
        else if (i < 1536) v = bff2g[i - 1280];
        else if (i < 1792) v = btag[i - 1536];
        else if (i < 2048) v = btbg[i - 1792];
        else               v = boutg[i - 2048];
        biasbuf[i] = v;
    }
    for (int e = tid; e < BT * Hh; e += 512) {
        int r = e >> 8, c = e & 255;
        zbuf[r][Ff + c] = (_Float16)0.0f;
    }
    for (int e = tid; e < BT * Ff; e += 512) {
        int r = e >> 7, f = e & 127;
        zbuf[r][f] = (_Float16)x[(size_t)(r0 + r) * Tt * Ff + f];
    }
    __syncthreads();

    const _Float16* Az  = &zbuf[lc][lg * 8];
    const _Float16* Az1 = &z1buf[lc][lg * 8];
    const _Float16* Az2 = &z2buf[lc][lg * 8];
    const _Float16* Ah  = &zbuf[lc][Ff + lg * 8];

    for (int t = 0; t < Tt; ++t) {
        // ---- phase 1: z1 = lecun(z @ W1 + b1), [16,384]@[384,512] ----
        {
            f32x4 acc[4];
#pragma unroll
            for (int r = 0; r < 4; ++r) acc[r] = zero4();
            const _Float16* Bp[4];
#pragma unroll
            for (int r = 0; r < 4; ++r) Bp[r] = w1f + ((4 * w + r) * 12) * 512 + l * 8;
            run_gemm<4, 12>(acc, Az, Bp);
#pragma unroll
            for (int r = 0; r < 4; ++r) {
                int col = (4 * w + r) * 16 + lc;
                float bb = biasbuf[col];
#pragma unroll
                for (int i = 0; i < 4; ++i)
                    z1buf[lg * 4 + i][col] = (_Float16)lecun_act(acc[r][i] + bb);
            }
        }
        __syncthreads();
        // ---- phase 2: z2 = lecun(z1 @ W2 + b2), [16,512]@[512,512] ----
        {
            f32x4 acc[4];
#pragma unroll
            for (int r = 0; r < 4; ++r) acc[r] = zero4();
            const _Float16* Bp[4];
#pragma unroll
            for (int r = 0; r < 4; ++r) Bp[r] = w2f + ((4 * w + r) * 16) * 512 + l * 8;
            run_gemm<4, 16>(acc, Az1, Bp);
#pragma unroll
            for (int r = 0; r < 4; ++r) {
                int col = (4 * w + r) * 16 + lc;
                float bb = biasbuf[512 + col];
#pragma unroll
                for (int i = 0; i < 4; ++i)
                    z2buf[lg * 4 + i][col] = (_Float16)lecun_act(acc[r][i] + bb);
            }
        }
        __syncthreads();
        // ---- phase 3: four heads + gate -> h_new into zbuf[:,F:] ----
        {
            f32x4 acc[8];
#pragma unroll
            for (int r = 0; r < 8; ++r) acc[r] = zero4();
            const _Float16* Bp[8];
#pragma unroll
            for (int h = 0; h < 4; ++h)
#pragma unroll
                for (int c = 0; c < 2; ++c)
                    Bp[h * 2 + c] = whf + ((h * 16 + 2 * w + c) * 16) * 512 + l * 8;
            run_gemm<8, 16>(acc, Az2, Bp);
#pragma unroll
            for (int c = 0; c < 2; ++c) {
                int col = (2 * w + c) * 16 + lc;   // h column 0..255
                float bf1 = biasbuf[1024 + col];
                float bf2 = biasbuf[1280 + col];
                float bA  = biasbuf[1536 + col];
                float bB  = biasbuf[1792 + col];
#pragma unroll
                for (int i = 0; i < 4; ++i) {
                    int row = lg * 4 + i;
                    float ff1 = fast_tanh(acc[0 + c][i] + bf1);
                    float ff2 = fast_tanh(acc[2 + c][i] + bf2);
                    float tav = acc[4 + c][i] + bA;
                    float tbv = acc[6 + c][i] + bB;
                    float tsc = ts[(size_t)(r0 + row) * Tt + t] * (1.0f / 256.0f);
                    float s   = fast_sigmoid(tav * tsc + tbv);
                    float hv  = ff1 + s * (ff2 - ff1);
                    zbuf[row][Ff + col] = (_Float16)hv;
                }
            }
        }
        __syncthreads();
        // ---- phase 4: out(t) = h_new @ Wout + bout  (+ prefill x(t+1)) ----
        {
            if (t + 1 < Tt) {
                for (int e = tid; e < BT * Ff; e += 512) {
                    int r = e >> 7, f = e & 127;
                    zbuf[r][f] = (_Float16)x[((size_t)(r0 + r) * Tt + (t + 1)) * Ff + f];
                }
            }
            f32x4 acc[1];
            acc[0] = zero4();
            const _Float16* Bp[1] = { wof + (w * 8) * 512 + l * 8 };
            run_gemm<1, 8>(acc, Ah, Bp);
            int col = w * 16 + lc;
            float bo = biasbuf[2048 + col];
#pragma unroll
            for (int i = 0; i < 4; ++i) {
                int row = lg * 4 + i;
                out[((size_t)(r0 + row) * Tt + t) * OUTo + col] = acc[0][i] + bo;
            }
        }
        __syncthreads();
    }
}

extern "C" void kernel_launch(void* const* d_in, const int* in_sizes, int n_in,
                              void* d_out, int out_size, void* d_ws, size_t ws_size,
                              hipStream_t stream) {
    const float* x    = (const float*)d_in[0];
    const float* ts   = (const float*)d_in[1];
    const float* W1   = (const float*)d_in[2];
    const float* b1   = (const float*)d_in[3];
    const float* W2   = (const float*)d_in[4];
    const float* b2   = (const float*)d_in[5];
    const float* Wff1 = (const float*)d_in[6];
    const float* bff1 = (const float*)d_in[7];
    const float* Wff2 = (const float*)d_in[8];
    const float* bff2 = (const float*)d_in[9];
    const float* Wta  = (const float*)d_in[10];
    const float* bta  = (const float*)d_in[11];
    const float* Wtb  = (const float*)d_in[12];
    const float* btb  = (const float*)d_in[13];
    const float* Wout = (const float*)d_in[14];
    const float* bout = (const float*)d_in[15];
    float* out = (float*)d_out;
    _Float16* wf = (_Float16*)d_ws;

    prep_weights<<<(WTOT + 255) / 256, 256, 0, stream>>>(W1, W2, Wff1, Wff2, Wta, Wtb, Wout, wf);
    cfc_main<<<NBLK, 512, 0, stream>>>(x, ts, b1, b2, bff1, bff2, bta, btb, bout, wf, out);
}

// Round 2
// 5072.900 us; speedup vs baseline: 3.4177x; 3.4177x over previous
//
#include <hip/hip_runtime.h>

typedef _Float16 f16x8 __attribute__((ext_vector_type(8)));
typedef _Float16 f16x4 __attribute__((ext_vector_type(4)));
typedef float    f32x4 __attribute__((ext_vector_type(4)));

#define DEVINL __device__ __forceinline__

namespace {
constexpr int Tt = 256, Ff = 128, Hh = 256, Uu = 512, OUTo = 128;
constexpr int BT = 16;                  // batch rows per block
constexpr int NBLK = 32;                // 512 / 16
constexpr int FRAGS = 1984;             // 1KB fragments per step (12+16+32+2)*32
constexpr int CHUNK_F16 = 16384;        // 32KB chunk in f16 elems
constexpr int NCHUNK = 62;              // chunks per step
constexpr int STAGE_BYTES = 3 * 32768;  // triple buffer
}

// ---- weight prep: f32 row-major -> fp16 fragment STREAM in consumption order ----
// stream frag order: phase1 [kt 0..11][nt 0..31] | phase2 [kt 0..15][nt 0..31]
//                  | phase3 [kt 0..15][ct 0..15][head 0..3] | phase4 [kt 0..7][nt 0..7]
// frag internal: elem(l,j) = W[kt*32 + (l>>4)*8 + j][nt*16 + (l&15)]
__global__ void prep_weights(const float* __restrict__ W1, const float* __restrict__ W2,
                             const float* __restrict__ Wff1, const float* __restrict__ Wff2,
                             const float* __restrict__ Wta, const float* __restrict__ Wtb,
                             const float* __restrict__ Wout, _Float16* __restrict__ ws)
{
    int o = blockIdx.x * blockDim.x + threadIdx.x;
    if (o >= FRAGS * 512) return;
    int j = o & 7, l = (o >> 3) & 63, f = o >> 9;
    int k_in = ((l >> 4) << 3) + j;     // 0..31 within a kt
    int lc = l & 15;
    const float* W; int N, kt, col;
    if (f < 384)        { W = W1; N = Uu; kt = f >> 5; col = ((f & 31) << 4) + lc; }
    else if (f < 896)   { int g = f - 384; W = W2; N = Uu; kt = g >> 5; col = ((g & 31) << 4) + lc; }
    else if (f < 1920)  { int g = f - 896; kt = g >> 6; int p = g & 63; int ct = p >> 2, h = p & 3;
                          W = (h == 0) ? Wff1 : (h == 1) ? Wff2 : (h == 2) ? Wta : Wtb;
                          N = Hh; col = (ct << 4) + lc; }
    else                { int g = f - 1920; W = Wout; N = OUTo; kt = g >> 3; col = ((g & 7) << 4) + lc; }
    ws[o] = (_Float16)W[(kt * 32 + k_in) * N + col];
}

// ---------------- activation helpers ----------------
DEVINL float fast_tanh(float v) {
    float e = __expf(2.0f * v);
    return 1.0f - 2.0f / (e + 1.0f);
}
DEVINL float fast_sigmoid(float v) { return 1.0f / (1.0f + __expf(-v)); }
DEVINL float lecun_act(float v)    { return 1.7159f * fast_tanh(0.666f * v); }

// ---- async global->LDS, 16B per lane, one wave-wide 1KB write per call ----
DEVINL void gl_lds16(const void* g, void* s) {
    __builtin_amdgcn_global_load_lds((const __attribute__((address_space(1))) void*)g,
                                     (__attribute__((address_space(3))) void*)s, 16, 0, 0);
}

// stage one 32KB chunk: wave w stages bytes [w*2048, w*2048+2048)
DEVINL void stage_chunk(const _Float16* wsf, _Float16* stage, int sp, int sbuf, int w, int l) {
    const char* g = (const char*)wsf + (size_t)sp * 32768 + w * 2048 + l * 16;
    char* s = (char*)stage + sbuf * 32768 + w * 2048;
    gl_lds16(g, s);
    gl_lds16(g + 1024, s + 1024);
}

#define CHUNK_SYNC() do { \
    asm volatile("s_waitcnt vmcnt(2)" ::: "memory"); \
    asm volatile("s_waitcnt lgkmcnt(0)" ::: "memory"); \
    __builtin_amdgcn_s_barrier(); \
    asm volatile("" ::: "memory"); \
    __builtin_amdgcn_sched_barrier(0); \
} while (0)

#define ADV3(v) ((v) == 2 ? 0 : (v) + 1)
#define ADV62(v) ((v) == NCHUNK - 1 ? 0 : (v) + 1)

__global__ __launch_bounds__(1024)
void cfc_main(const float* __restrict__ x, const float* __restrict__ ts,
              const float* __restrict__ b1g, const float* __restrict__ b2g,
              const float* __restrict__ bff1g, const float* __restrict__ bff2g,
              const float* __restrict__ btag, const float* __restrict__ btbg,
              const float* __restrict__ boutg,
              const _Float16* __restrict__ wsf,
              float* __restrict__ out)
{
    __shared__ _Float16 zbuf[BT][392];      // [x 0:128 | h 128:384], pad to 392
    __shared__ _Float16 z1buf[BT][Uu + 8];
    __shared__ _Float16 z2buf[BT][Uu + 8];
    __shared__ float    biasbuf[2176];      // b1|b2|bff1|bff2|bta|btb|bout
    __shared__ float    tsbuf[BT];
    extern __shared__ __align__(16) _Float16 stage[];   // 3 x 16384 f16 = 96KB

    const int tid = threadIdx.x;
    const int l = tid & 63, w = tid >> 6;   // 16 waves
    const int lc = l & 15, lg = l >> 4;
    const int r0 = blockIdx.x * BT;

    // ---- prologue ----
    for (int i = tid; i < 2176; i += 1024) {
        float v;
        if      (i < 512)  v = b1g[i];
        else if (i < 1024) v = b2g[i - 512];
        else if (i < 1280) v = bff1g[i - 1024];
        else if (i < 1536) v = bff2g[i - 1280];
        else if (i < 1792) v = btag[i - 1536];
        else if (i < 2048) v = btbg[i - 1792];
        else               v = boutg[i - 2048];
        biasbuf[i] = v;
    }
    for (int e = tid; e < BT * Hh; e += 1024)
        zbuf[e >> 8][Ff + (e & 255)] = (_Float16)0.0f;
    for (int e = tid; e < BT * Ff; e += 1024)
        zbuf[e >> 7][e & 127] = (_Float16)x[(size_t)(r0 + (e >> 7)) * Tt * Ff + (e & 127)];
    if (tid < BT) tsbuf[tid] = ts[(size_t)(r0 + tid) * Tt];
    stage_chunk(wsf, stage, 0, 0, w, l);
    stage_chunk(wsf, stage, 1, 1, w, l);
    __syncthreads();   // drains the two prologue stages too (once, fine)

    const _Float16* Az  = &zbuf[lc][lg * 8];
    const _Float16* Az1 = &z1buf[lc][lg * 8];
    const _Float16* Az2 = &z2buf[lc][lg * 8];
    const _Float16* Ah  = &zbuf[lc][Ff + lg * 8];

    int sp = 2;     // next stream chunk to stage (mod 62)
    int cbuf = 0;   // LDS buffer of current compute chunk (mod 3)

    for (int t = 0; t < Tt; ++t) {
        // ---- phase 1: z1 = lecun(z @ W1 + b1)  [12 chunks, 1 kt each] ----
        {
            f32x4 a0 = {0.f,0.f,0.f,0.f}, a1 = {0.f,0.f,0.f,0.f};
            for (int kt = 0; kt < 12; ++kt) {
                CHUNK_SYNC();
                int sb = cbuf + 2; if (sb >= 3) sb -= 3;
                stage_chunk(wsf, stage, sp, sb, w, l); sp = ADV62(sp);
                const _Float16* S = stage + cbuf * CHUNK_F16;
                f16x8 av = *(const f16x8*)(Az + kt * 32);
                f16x8 b0 = *(const f16x8*)(S + (2 * w) * 512 + l * 8);
                f16x8 b1 = *(const f16x8*)(S + (2 * w + 1) * 512 + l * 8);
                a0 = __builtin_amdgcn_mfma_f32_16x16x32_f16(av, b0, a0, 0, 0, 0);
                a1 = __builtin_amdgcn_mfma_f32_16x16x32_f16(av, b1, a1, 0, 0, 0);
                cbuf = ADV3(cbuf);
            }
#pragma unroll
            for (int r = 0; r < 2; ++r) {
                int col = (2 * w + r) * 16 + lc;
                float bb = biasbuf[col];
                f32x4 av = r ? a1 : a0;
#pragma unroll
                for (int i = 0; i < 4; ++i)
                    z1buf[lg * 4 + i][col] = (_Float16)lecun_act(av[i] + bb);
            }
        }
        // ---- phase 2: z2 = lecun(z1 @ W2 + b2)  [16 chunks] ----
        {
            f32x4 a0 = {0.f,0.f,0.f,0.f}, a1 = {0.f,0.f,0.f,0.f};
            for (int kt = 0; kt < 16; ++kt) {
                CHUNK_SYNC();
                int sb = cbuf + 2; if (sb >= 3) sb -= 3;
                stage_chunk(wsf, stage, sp, sb, w, l); sp = ADV62(sp);
                const _Float16* S = stage + cbuf * CHUNK_F16;
                f16x8 av = *(const f16x8*)(Az1 + kt * 32);
                f16x8 b0 = *(const f16x8*)(S + (2 * w) * 512 + l * 8);
                f16x8 b1 = *(const f16x8*)(S + (2 * w + 1) * 512 + l * 8);
                a0 = __builtin_amdgcn_mfma_f32_16x16x32_f16(av, b0, a0, 0, 0, 0);
                a1 = __builtin_amdgcn_mfma_f32_16x16x32_f16(av, b1, a1, 0, 0, 0);
                cbuf = ADV3(cbuf);
            }
#pragma unroll
            for (int r = 0; r < 2; ++r) {
                int col = (2 * w + r) * 16 + lc;
                float bb = biasbuf[512 + col];
                f32x4 av = r ? a1 : a0;
#pragma unroll
                for (int i = 0; i < 4; ++i)
                    z2buf[lg * 4 + i][col] = (_Float16)lecun_act(av[i] + bb);
            }
        }
        // ---- phase 3: four heads + gate -> h  [32 chunks: kt x half] ----
        {
            f32x4 ah0 = {0.f,0.f,0.f,0.f}, ah1 = {0.f,0.f,0.f,0.f};
            f32x4 ah2 = {0.f,0.f,0.f,0.f}, ah3 = {0.f,0.f,0.f,0.f};
            for (int c3 = 0; c3 < 32; ++c3) {
                CHUNK_SYNC();
                int sb = cbuf + 2; if (sb >= 3) sb -= 3;
                stage_chunk(wsf, stage, sp, sb, w, l); sp = ADV62(sp);
                int kt = c3 >> 1, half = c3 & 1;
                if ((w >> 3) == half) {       // wave w owns head-col-tile ct = w
                    const _Float16* S = stage + cbuf * CHUNK_F16;
                    int pb = (w & 7) * 4;
                    f16x8 av = *(const f16x8*)(Az2 + kt * 32);
                    f16x8 b0 = *(const f16x8*)(S + (pb + 0) * 512 + l * 8);
                    f16x8 b1 = *(const f16x8*)(S + (pb + 1) * 512 + l * 8);
                    f16x8 b2 = *(const f16x8*)(S + (pb + 2) * 512 + l * 8);
                    f16x8 b3 = *(const f16x8*)(S + (pb + 3) * 512 + l * 8);
                    ah0 = __builtin_amdgcn_mfma_f32_16x16x32_f16(av, b0, ah0, 0, 0, 0);
                    ah1 = __builtin_amdgcn_mfma_f32_16x16x32_f16(av, b1, ah1, 0, 0, 0);
                    ah2 = __builtin_amdgcn_mfma_f32_16x16x32_f16(av, b2, ah2, 0, 0, 0);
                    ah3 = __builtin_amdgcn_mfma_f32_16x16x32_f16(av, b3, ah3, 0, 0, 0);
                }
                cbuf = ADV3(cbuf);
            }
            int col = w * 16 + lc;            // h column 0..255
            float bf1 = biasbuf[1024 + col];
            float bf2 = biasbuf[1280 + col];
            float bA  = biasbuf[1536 + col];
            float bB  = biasbuf[1792 + col];
#pragma unroll
            for (int i = 0; i < 4; ++i) {
                int row = lg * 4 + i;
                float tsc = tsbuf[row] * (1.0f / 256.0f);
                float ff1 = fast_tanh(ah0[i] + bf1);
                float ff2 = fast_tanh(ah1[i] + bf2);
                float s   = fast_sigmoid((ah2[i] + bA) * tsc + (ah3[i] + bB));
                zbuf[row][Ff + col] = (_Float16)(ff1 + s * (ff2 - ff1));
            }
        }
        // ---- phase 4: out = h @ Wout + bout  [2 chunks] + prefill x(t+1), ts(t+1) ----
        {
            f32x4 ao = {0.f,0.f,0.f,0.f};
            for (int c4 = 0; c4 < 2; ++c4) {
                CHUNK_SYNC();
                f32x4 xv;
                float tsv = 0.f;
                if (w >= 8 && c4 == 0 && t + 1 < Tt) {
                    int tid2 = tid - 512;                 // 0..511
                    int row = tid2 >> 5, q = tid2 & 31;
                    xv = *(const f32x4*)(x + ((size_t)(r0 + row) * Tt + (t + 1)) * Ff + q * 4);
                    if (w == 8 && l < BT) tsv = ts[(size_t)(r0 + l) * Tt + (t + 1)];
                }
                int sb = cbuf + 2; if (sb >= 3) sb -= 3;
                stage_chunk(wsf, stage, sp, sb, w, l); sp = ADV62(sp);
                if (w < 8) {
                    const _Float16* S = stage + cbuf * CHUNK_F16;
#pragma unroll
                    for (int q = 0; q < 4; ++q) {
                        int kt = c4 * 4 + q;
                        f16x8 av = *(const f16x8*)(Ah + kt * 32);
                        f16x8 bv = *(const f16x8*)(S + (q * 8 + w) * 512 + l * 8);
                        ao = __builtin_amdgcn_mfma_f32_16x16x32_f16(av, bv, ao, 0, 0, 0);
                    }
                } else if (c4 == 0 && t + 1 < Tt) {
                    int tid2 = tid - 512;
                    int row = tid2 >> 5, q = tid2 & 31;
                    f16x4 hv = { (_Float16)xv[0], (_Float16)xv[1], (_Float16)xv[2], (_Float16)xv[3] };
                    *(f16x4*)(&zbuf[row][q * 4]) = hv;
                    if (w == 8 && l < BT) tsbuf[l] = tsv;
                }
                cbuf = ADV3(cbuf);
            }
            if (w < 8) {
                int col = w * 16 + lc;
                float bo = biasbuf[2048 + col];
#pragma unroll
                for (int i = 0; i < 4; ++i)
                    out[((size_t)(r0 + lg * 4 + i) * Tt + t) * OUTo + col] = ao[i] + bo;
            }
        }
    }
    asm volatile("s_waitcnt vmcnt(0)" ::: "memory");   // drain tail stages before LDS dealloc
}

extern "C" void kernel_launch(void* const* d_in, const int* in_sizes, int n_in,
                              void* d_out, int out_size, void* d_ws, size_t ws_size,
                              hipStream_t stream) {
    const float* x    = (const float*)d_in[0];
    const float* ts   = (const float*)d_in[1];
    const float* W1   = (const float*)d_in[2];
    const float* b1   = (const float*)d_in[3];
    const float* W2   = (const float*)d_in[4];
    const float* b2   = (const float*)d_in[5];
    const float* Wff1 = (const float*)d_in[6];
    const float* bff1 = (const float*)d_in[7];
    const float* Wff2 = (const float*)d_in[8];
    const float* bff2 = (const float*)d_in[9];
    const float* Wta  = (const float*)d_in[10];
    const float* bta  = (const float*)d_in[11];
    const float* Wtb  = (const float*)d_in[12];
    const float* btb  = (const float*)d_in[13];
    const float* Wout = (const float*)d_in[14];
    const float* bout = (const float*)d_in[15];
    float* out = (float*)d_out;
    _Float16* wf = (_Float16*)d_ws;

    static bool attr_set = false;
    (void)attr_set;
    hipFuncSetAttribute((const void*)cfc_main,
                        hipFuncAttributeMaxDynamicSharedMemorySize, STAGE_BYTES);

    prep_weights<<<(FRAGS * 512) / 256, 256, 0, stream>>>(W1, W2, Wff1, Wff2, Wta, Wtb, Wout, wf);
    cfc_main<<<NBLK, 1024, STAGE_BYTES, stream>>>(x, ts, b1, b2, bff1, bff2, bta, btb, bout, wf, out);
}